// Round 11
// baseline (431.575 us; speedup 1.0000x reference)
//
#include <hip/hip_runtime.h>
#include <hip/hip_fp16.h>
#include <cstdint>
#include <cstddef>

typedef _Float16 f16;
typedef __attribute__((ext_vector_type(4))) _Float16 f16x4;
typedef __attribute__((ext_vector_type(8))) _Float16 f16x8;
typedef __attribute__((ext_vector_type(4))) float f32x4;

#define C_INV_SQRT2 0.70710678118654752440f

__device__ __forceinline__ void gld_lds16(const void* g, void* l) {
  __builtin_amdgcn_global_load_lds((const __attribute__((address_space(1))) void*)g,
                                   (__attribute__((address_space(3))) void*)l, 16, 0, 0);
}

// ---------------- conversion kernels ----------------
__global__ __launch_bounds__(256) void cvt_f32_f16_k(const float* __restrict__ in,
                                                     f16* __restrict__ out, int n4) {
  int i = blockIdx.x * 256 + threadIdx.x;
  if (i >= n4) return;
  const float4 x = ((const float4*)in)[i];
  f16x4 y;
  y.x = (f16)x.x; y.y = (f16)x.y; y.z = (f16)x.z; y.w = (f16)x.w;
  ((f16x4*)out)[i] = y;
}

// pack W_qkv rows {0..1023} and {2048..3071} into Wo[2048][1024] f16; same for bias
__global__ __launch_bounds__(256) void pack_wqv_k(const float* __restrict__ W,
                                                  const float* __restrict__ b,
                                                  f16* __restrict__ Wo,
                                                  float* __restrict__ bo) {
  int i = blockIdx.x * 256 + threadIdx.x;
  int n = i >> 8;
  int c = (i & 255) * 4;
  int sn = (n < 1024) ? n : (n + 1024);
  const float4 x = *(const float4*)(W + (size_t)sn * 1024 + c);
  f16x4 y; y.x = (f16)x.x; y.y = (f16)x.y; y.z = (f16)x.z; y.w = (f16)x.w;
  *(f16x4*)(Wo + (size_t)n * 1024 + c) = y;
  if (i < 2048) bo[i] = b[(i < 1024) ? i : (i + 1024)];
}

// -------- 3-level Haar forward + weighted product + inverse, 8 samples --------
__device__ __forceinline__ void haar_mid(const f16x8 q8, const f16x8 v8,
                                         float wq0, float wq1, float wq2,
                                         float wv0, float wv1, float wv2,
                                         float* a8) {
  const float c = C_INV_SQRT2;
  float q[8], v[8];
#pragma unroll
  for (int i = 0; i < 8; i++) { q[i] = (float)q8[i]; v[i] = (float)v8[i]; }
  float qa1[4], qd1[4], va1[4], vd1[4];
#pragma unroll
  for (int i = 0; i < 4; i++) {
    qd1[i] = (q[2 * i] - q[2 * i + 1]) * c;
    qa1[i] = (q[2 * i] + q[2 * i + 1]) * c;
    vd1[i] = (v[2 * i] - v[2 * i + 1]) * c;
    va1[i] = (v[2 * i] + v[2 * i + 1]) * c;
  }
  float qa2[2], qd2[2], va2[2], vd2[2];
#pragma unroll
  for (int j = 0; j < 2; j++) {
    qd2[j] = (qa1[2 * j] - qa1[2 * j + 1]) * c;
    qa2[j] = (qa1[2 * j] + qa1[2 * j + 1]) * c;
    vd2[j] = (va1[2 * j] - va1[2 * j + 1]) * c;
    va2[j] = (va1[2 * j] + va1[2 * j + 1]) * c;
  }
  const float qd3 = (qa2[0] - qa2[1]) * c, qa3 = (qa2[0] + qa2[1]) * c;
  const float vd3 = (va2[0] - va2[1]) * c, va3 = (va2[0] + va2[1]) * c;
  const float pa = (qa3 * wq0) * (va3 * wv0);
  const float pd3 = (qd3 * wq1) * (vd3 * wv1);
  float pd2[2], pd1[4];
#pragma unroll
  for (int j = 0; j < 2; j++) pd2[j] = (qd2[j] * wq2) * (vd2[j] * wv2);
#pragma unroll
  for (int i = 0; i < 4; i++) pd1[i] = qd1[i] * vd1[i];
  float s2[2], s1[4];
  s2[0] = (pa + pd3) * c;
  s2[1] = (pa - pd3) * c;
#pragma unroll
  for (int j = 0; j < 2; j++) {
    s1[2 * j] = (s2[j] + pd2[j]) * c;
    s1[2 * j + 1] = (s2[j] - pd2[j]) * c;
  }
#pragma unroll
  for (int i = 0; i < 4; i++) {
    a8[2 * i] = (s1[i] + pd1[i]) * c;
    a8[2 * i + 1] = (s1[i] - pd1[i]) * c;
  }
}

// ---- 256x256 GEMM, 8 waves (2M x 4N), R8 4-phase/K-tile schedule ----
// AF32=true: A operand is fp32 in global; staged via registers (issue 8x
//   global_load_dwordx4 at p0 -> cvt f32->f16 + 4x ds_write_b128 at p2).
//   Register data-dep makes the compiler scoreboard the A-loads; the manual
//   vmcnt ledger below only covers B's global_load_lds.
// FUSED=true: B panel = W rows {d0..+127} U {1024+d0..+127}; epilogue runs the
//   Haar middle via transposed XOR-swizzled LDS c-tile and writes a[M][1024].
// vmcnt ledger (B gld_lds only; A-reg loads drained by compiler at p2):
//   p0 entry: outstanding = Bh(t) 4 glds (issued p0/p1 of t-1, 2-3 phases old)
//             -> vmcnt(0) (cheap drain).  A(t+2) issue + Bh0(t+1) stage in body.
//   p2: lgkm(0)+barrier certify all waves' Ah(t) reads returned -> ds_write
//       Ah(t+2) into same-buf A halves is safe.
// LDS swizzle: chunk' = chunk ^ (row&7), both-sides (verified 0 conflicts).
// T1 bijective XCD swizzle (nwg % 8 == 0).  T5 setprio around MFMA clusters.

#define STAGEH(bufi, mat, half, Gbase, k0)                         \
  {                                                                \
    f16* Ld = &lds[bufi][mat][half][0];                            \
    const f16* Gp = (Gbase) + (size_t)srow * K + (k0) + sch * 8;   \
    gld_lds16(Gp, Ld + (w * 64) * 8);                              \
    gld_lds16(Gp + (size_t)64 * K, Ld + (4096 + w * 64 * 8));      \
  }

// issue 8 dwordx4 f32 loads for A(tile at k0); slice sl covers rows sl*64+srow
#define A_ISSUE(k0)                                                          \
  {                                                                          \
    _Pragma("unroll") for (int sl = 0; sl < 4; sl++) {                       \
      const float* gp = A32 + (size_t)(m0 + sl * 64 + srow) * K + (k0) + sch * 8; \
      ar[sl][0] = *(const float4*)gp;                                        \
      ar[sl][1] = *(const float4*)(gp + 4);                                  \
    }                                                                        \
  }

// cvt + ds_write the staged A into buf's A halves (linear dest, same as gld_lds)
#define A_WRITE(bufi)                                                        \
  {                                                                          \
    _Pragma("unroll") for (int sl = 0; sl < 4; sl++) {                       \
      f16x8 y;                                                               \
      _Pragma("unroll") for (int j = 0; j < 4; j++) {                        \
        y[j] = (f16)ar[sl][0][j];                                            \
        y[j + 4] = (f16)ar[sl][1][j];                                        \
      }                                                                      \
      *(f16x8*)(&lds[bufi][0][sl >> 1][0] + ((sl & 1) * 512 + t) * 8) = y;   \
    }                                                                        \
  }

#define MFMA_PH(mi0)                                                             \
  __builtin_amdgcn_s_setprio(1);                                                 \
  _Pragma("unroll") for (int mm = (mi0); mm < (mi0) + 2; mm++)                   \
      _Pragma("unroll") for (int nj = 0; nj < 4; nj++) {                         \
    acc[mm][nj] = __builtin_amdgcn_mfma_f32_16x16x32_f16(aF[mm][0], bF[nj][0],   \
                                                         acc[mm][nj], 0, 0, 0);  \
    acc[mm][nj] = __builtin_amdgcn_mfma_f32_16x16x32_f16(aF[mm][1], bF[nj][1],   \
                                                         acc[mm][nj], 0, 0, 0);  \
  }                                                                              \
  __builtin_amdgcn_s_setprio(0);

#define BAR_SEQ()                       \
  __builtin_amdgcn_sched_barrier(0);    \
  __builtin_amdgcn_s_barrier();         \
  __builtin_amdgcn_sched_barrier(0);

template <typename CT, bool FUSED, bool AF32>
__global__ __launch_bounds__(512, 2) void gemm256_k(const f16* __restrict__ A,
                                                    const f16* __restrict__ B,
                                                    const float* __restrict__ bias,
                                                    CT* __restrict__ C,
                                                    const float* __restrict__ wq,
                                                    const float* __restrict__ wv,
                                                    const float* __restrict__ A32,
                                                    int M, int N, int K, int nbx) {
  __shared__ f16 lds[2][2][2][128 * 64];  // 128 KiB
  const int t = threadIdx.x;
  const int w = t >> 6, l = t & 63;
  const int wm = w >> 2, wn = w & 3;  // 2 x 4 wave grid
  const int hi = l >> 4, lo = l & 15;

  // T1: bijective XCD swizzle (nwg % 8 == 0)
  const int nwg = gridDim.x;
  const int cpx = nwg >> 3;
  const int bid = blockIdx.x;
  const int nid = (bid & 7) * cpx + (bid >> 3);
  const int by = nid / nbx, bx = nid - by * nbx;
  const int m0 = by * 256;
  const int n0 = bx * 256;   // non-fused col base
  const int d0 = bx * 128;   // fused dim base

  const f16* GA = A + (size_t)m0 * K;
  const f16* GBq = FUSED ? (B + (size_t)d0 * K) : (B + (size_t)n0 * K);
  const f16* GBv = FUSED ? (B + (size_t)(1024 + d0) * K) : (GBq + (size_t)128 * K);

  // staging slot map: load i covers slot u = i*512 + t per half-plane;
  // row = u>>3, chunk = (u&7) ^ (row&7)  [inverse swizzle on source]
  const int srow = t >> 3;
  const int sch = (t & 7) ^ (srow & 7);

  const int colk0 = ((hi ^ (lo & 7)) << 3);
  const int colk1 = (((4 | hi) ^ (lo & 7)) << 3);

  f32x4 acc[8][4] = {};
  f16x8 aF[8][2], bF[4][2];
  float4 ar[4][2];
  const int NT = K >> 6;  // 16

  // prologue
  STAGEH(0, 1, 0, GBq, 0);
  STAGEH(0, 1, 1, GBv, 0);
  if (AF32) {
    A_ISSUE(0);  A_WRITE(0);   // compiler waits on ar data-dep
    A_ISSUE(64); A_WRITE(1);
    asm volatile("s_waitcnt lgkmcnt(0)" ::: "memory");
  } else {
    STAGEH(0, 0, 0, GA, 0); STAGEH(0, 0, 1, GA + (size_t)128 * K, 0);
    STAGEH(1, 0, 0, GA, 64); STAGEH(1, 0, 1, GA + (size_t)128 * K, 64);
  }

  for (int tt = 0; tt < NT; ++tt) {
    const int buf = tt & 1;
    const f16* pA = &lds[buf][0][wm][0] + lo * 64;
    const f16* pB = &lds[buf][1][wn >> 1][0] + (wn & 1) * 4096 + lo * 64;
    const f16* pA0 = pA + colk0;
    const f16* pA1 = pA + colk1;
    const f16* pB0 = pB + colk0;
    const f16* pB1 = pB + colk1;

    // phase 0
    if (AF32) {
      asm volatile("s_waitcnt vmcnt(0)" ::: "memory");  // B(t) glds (2-3 phases old)
    } else {
      if (tt < NT - 1) {
        asm volatile("s_waitcnt vmcnt(4)" ::: "memory");
      } else {
        asm volatile("s_waitcnt vmcnt(0)" ::: "memory");
      }
    }
    BAR_SEQ();
    aF[0][0] = *(const f16x8*)(pA0 + 0 * 1024);
    aF[0][1] = *(const f16x8*)(pA1 + 0 * 1024);
    aF[1][0] = *(const f16x8*)(pA0 + 1 * 1024);
    aF[1][1] = *(const f16x8*)(pA1 + 1 * 1024);
#pragma unroll
    for (int nj = 0; nj < 4; nj++) {
      bF[nj][0] = *(const f16x8*)(pB0 + nj * 1024);
      bF[nj][1] = *(const f16x8*)(pB1 + nj * 1024);
    }
    aF[2][0] = *(const f16x8*)(pA0 + 2 * 1024);
    aF[2][1] = *(const f16x8*)(pA1 + 2 * 1024);
    aF[3][0] = *(const f16x8*)(pA0 + 3 * 1024);
    aF[3][1] = *(const f16x8*)(pA1 + 3 * 1024);
    if (AF32 && tt + 2 < NT) A_ISSUE((tt + 2) * 64);
    if (tt + 1 < NT) STAGEH(buf ^ 1, 1, 0, GBq, (tt + 1) * 64);
    MFMA_PH(0);

    // phase 1
    BAR_SEQ();
#pragma unroll
    for (int mi = 4; mi < 8; mi++) {
      aF[mi][0] = *(const f16x8*)(pA0 + mi * 1024);
      aF[mi][1] = *(const f16x8*)(pA1 + mi * 1024);
    }
    if (tt + 1 < NT) STAGEH(buf ^ 1, 1, 1, GBv, (tt + 1) * 64);
    MFMA_PH(2);

    // phase 2: all waves' Ah(t) reads returned (lgkm drain + barrier) ->
    // safe to overwrite same-buf A halves with tile t+2 data
    asm volatile("s_waitcnt lgkmcnt(0)" ::: "memory");
    BAR_SEQ();
    if (tt + 2 < NT) {
      if (AF32) {
        A_WRITE(buf);
      } else {
        STAGEH(buf, 0, 0, GA, (tt + 2) * 64);
      }
    }
    MFMA_PH(4);

    // phase 3
    asm volatile("s_waitcnt lgkmcnt(0)" ::: "memory");
    BAR_SEQ();
    if (!AF32 && tt + 2 < NT) STAGEH(buf, 0, 1, GA + (size_t)128 * K, (tt + 2) * 64);
    MFMA_PH(6);
  }

  if (!FUSED) {
    // plain epilogue: C/D layout col = lane&15, row = (lane>>4)*4 + reg
#pragma unroll
    for (int mi = 0; mi < 8; mi++) {
#pragma unroll
      for (int nj = 0; nj < 4; nj++) {
        const int col = n0 + wn * 64 + nj * 16 + lo;
        const float bb = bias[col];
        const size_t base = (size_t)(m0 + wm * 128 + mi * 16 + hi * 4) * N + col;
#pragma unroll
        for (int r = 0; r < 4; r++) C[base + (size_t)r * N] = (CT)(acc[mi][nj][r] + bb);
      }
    }
  } else {
    // fused Haar-middle epilogue (R9-verified).
    char* ctb = (char*)&lds[0][0][0][0];  // 128 KiB c-tile, LDS dead now
#pragma unroll
    for (int mi = 0; mi < 8; mi++) {
#pragma unroll
      for (int nj = 0; nj < 4; nj++) {
        const int col = wn * 64 + nj * 16 + lo;
        const int bidx = (col < 128) ? (d0 + col) : (1024 + d0 + col - 128);
        const float bb = bias[bidx];
        f16x4 y;
#pragma unroll
        for (int r = 0; r < 4; r++) y[r] = (f16)(acc[mi][nj][r] + bb);
        const int row2 = (wm * 128 + mi * 16 + hi * 4) * 2;
        const int byte = (col * 512 + row2) ^ ((col & 7) << 4);
        *(f16x4*)(ctb + byte) = y;
      }
    }
    asm volatile("s_waitcnt lgkmcnt(0)" ::: "memory");
    __builtin_amdgcn_s_barrier();
#pragma unroll 1
    for (int p = 0; p < 8; ++p) {
      const int c = t & 127;
      const int g = p * 4 + (t >> 7);
      const int byq = (c * 512 + g * 16) ^ ((c & 7) << 4);
      const f16x8 q8 = *(const f16x8*)(ctb + byq);
      const f16x8 v8 = *(const f16x8*)(ctb + byq + 65536);
      const int d = d0 + c;
      const int wb = (d >> 6) * 192 + (d & 63);
      float a8[8];
      haar_mid(q8, v8, wq[wb], wq[wb + 64], wq[wb + 128],
               wv[wb], wv[wb + 64], wv[wb + 128], a8);
      const size_t rb = (size_t)(m0 + g * 8) * 1024 + d;
#pragma unroll
      for (int i = 0; i < 8; i++) C[rb + (size_t)i * 1024] = (CT)a8[i];
    }
  }
}

// ---------------- standalone wavelet middle (ws-fallback path) ----------------
__global__ __launch_bounds__(256) void dwt_middle_k(const f16* __restrict__ qv,
                                                    const float* __restrict__ wq,
                                                    const float* __restrict__ wv,
                                                    f16* __restrict__ out) {
  const int g = blockIdx.x;
  const int d0 = threadIdx.x * 4;
  const size_t m0 = (size_t)g * 8;
  f16x4 qr[8], vr[8], o[8];
#pragma unroll
  for (int i = 0; i < 8; i++) {
    qr[i] = *(const f16x4*)(qv + (m0 + i) * 2048 + d0);
    vr[i] = *(const f16x4*)(qv + (m0 + i) * 2048 + 1024 + d0);
  }
#pragma unroll
  for (int dd = 0; dd < 4; dd++) {
    const int d = d0 + dd;
    const int wb = (d >> 6) * 192 + (d & 63);
    f16x8 q8, v8;
#pragma unroll
    for (int i = 0; i < 8; i++) { q8[i] = qr[i][dd]; v8[i] = vr[i][dd]; }
    float a8[8];
    haar_mid(q8, v8, wq[wb], wq[wb + 64], wq[wb + 128],
             wv[wb], wv[wb + 64], wv[wb + 128], a8);
#pragma unroll
    for (int i = 0; i < 8; i++) o[i][dd] = (f16)a8[i];
  }
#pragma unroll
  for (int i = 0; i < 8; i++) *(f16x4*)(out + (m0 + i) * 1024 + d0) = o[i];
}

// ---------------- launch ----------------
extern "C" void kernel_launch(void* const* d_in, const int* in_sizes, int n_in,
                              void* d_out, int out_size, void* d_ws, size_t ws_size,
                              hipStream_t stream) {
  (void)in_sizes; (void)n_in; (void)out_size;
  const float* query = (const float*)d_in[0];
  const float* W_qkv = (const float*)d_in[1];
  const float* b_qkv = (const float*)d_in[2];
  const float* W_out = (const float*)d_in[3];
  const float* b_out = (const float*)d_in[4];
  const float* wq = (const float*)d_in[5];
  const float* wv = (const float*)d_in[6];
  float* out = (float*)d_out;

  // workspace layout
  char* ws = (char*)d_ws;
  f16* qf16 = (f16*)ws;                                // 67,108,864 B (fallback only)
  f16* Wqv = (f16*)(ws + 67108864);                    //  4,194,304 B
  float* bqv = (float*)(ws + 67108864 + 4194304);      //      8,192 B
  f16* Wout = (f16*)(ws + 67108864 + 4194304 + 8192);  //  2,097,152 B
  const size_t OFS_A = 67108864UL + 4194304 + 8192 + 2097152;  // 73,408,512
  const size_t NEED = OFS_A + 67108864UL;                      // 140,517,376

  pack_wqv_k<<<dim3(2048), dim3(256), 0, stream>>>(W_qkv, b_qkv, Wqv, bqv);
  cvt_f32_f16_k<<<dim3(262144 / 256), dim3(256), 0, stream>>>(W_out, Wout, 262144);

  if (ws_size >= NEED) {
    // fused path: GEMM1 stages A from f32 query directly (no cvt kernel),
    // Haar middle in epilogue -> a in ws; no qv, no middle kernel
    f16* a_f16 = (f16*)(ws + OFS_A);
    gemm256_k<f16, true, true><<<dim3(8 * 128), dim3(512), 0, stream>>>(
        nullptr, Wqv, bqv, a_f16, wq, wv, query, 32768, 1024, 1024, 8);
    gemm256_k<float, false, false><<<dim3(4 * 128), dim3(512), 0, stream>>>(
        a_f16, Wout, b_out, out, nullptr, nullptr, nullptr, 32768, 1024, 1024, 4);
  } else {
    // fallback (R8-verified 3-kernel path): qv in d_out, a aliases qf16
    cvt_f32_f16_k<<<dim3(8388608 / 256), dim3(256), 0, stream>>>(query, qf16, 8388608);
    f16* qv = (f16*)d_out;
    f16* a_f16 = qf16;
    gemm256_k<f16, false, false><<<dim3(8 * 128), dim3(512), 0, stream>>>(
        qf16, Wqv, bqv, qv, nullptr, nullptr, nullptr, 32768, 2048, 1024, 8);
    dwt_middle_k<<<dim3(4096), dim3(256), 0, stream>>>(qv, wq, wv, a_f16);
    gemm256_k<float, false, false><<<dim3(4 * 128), dim3(512), 0, stream>>>(
        a_f16, Wout, b_out, out, nullptr, nullptr, nullptr, 32768, 1024, 1024, 4);
  }
}

// Round 12
// 367.400 us; speedup vs baseline: 1.1747x; 1.1747x over previous
//
#include <hip/hip_runtime.h>
#include <hip/hip_fp16.h>
#include <cstdint>
#include <cstddef>

typedef _Float16 f16;
typedef __attribute__((ext_vector_type(4))) _Float16 f16x4;
typedef __attribute__((ext_vector_type(8))) _Float16 f16x8;
typedef __attribute__((ext_vector_type(4))) float f32x4;

#define C_INV_SQRT2 0.70710678118654752440f

__device__ __forceinline__ void gld_lds16(const void* g, void* l) {
  __builtin_amdgcn_global_load_lds((const __attribute__((address_space(1))) void*)g,
                                   (__attribute__((address_space(3))) void*)l, 16, 0, 0);
}

// ---------------- conversion kernels ----------------
__global__ __launch_bounds__(256) void cvt_f32_f16_k(const float* __restrict__ in,
                                                     f16* __restrict__ out, int n4) {
  int i = blockIdx.x * 256 + threadIdx.x;
  if (i >= n4) return;
  const float4 x = ((const float4*)in)[i];
  f16x4 y;
  y.x = (f16)x.x; y.y = (f16)x.y; y.z = (f16)x.z; y.w = (f16)x.w;
  ((f16x4*)out)[i] = y;
}

// pack W_qkv rows {0..1023} and {2048..3071} into Wo[2048][1024] f16; same for bias
__global__ __launch_bounds__(256) void pack_wqv_k(const float* __restrict__ W,
                                                  const float* __restrict__ b,
                                                  f16* __restrict__ Wo,
                                                  float* __restrict__ bo) {
  int i = blockIdx.x * 256 + threadIdx.x;
  int n = i >> 8;
  int c = (i & 255) * 4;
  int sn = (n < 1024) ? n : (n + 1024);
  const float4 x = *(const float4*)(W + (size_t)sn * 1024 + c);
  f16x4 y; y.x = (f16)x.x; y.y = (f16)x.y; y.z = (f16)x.z; y.w = (f16)x.w;
  *(f16x4*)(Wo + (size_t)n * 1024 + c) = y;
  if (i < 2048) bo[i] = b[(i < 1024) ? i : (i + 1024)];
}

// -------- 3-level Haar forward + weighted product + inverse, 8 samples --------
__device__ __forceinline__ void haar_mid(const f16x8 q8, const f16x8 v8,
                                         float wq0, float wq1, float wq2,
                                         float wv0, float wv1, float wv2,
                                         float* a8) {
  const float c = C_INV_SQRT2;
  float q[8], v[8];
#pragma unroll
  for (int i = 0; i < 8; i++) { q[i] = (float)q8[i]; v[i] = (float)v8[i]; }
  float qa1[4], qd1[4], va1[4], vd1[4];
#pragma unroll
  for (int i = 0; i < 4; i++) {
    qd1[i] = (q[2 * i] - q[2 * i + 1]) * c;
    qa1[i] = (q[2 * i] + q[2 * i + 1]) * c;
    vd1[i] = (v[2 * i] - v[2 * i + 1]) * c;
    va1[i] = (v[2 * i] + v[2 * i + 1]) * c;
  }
  float qa2[2], qd2[2], va2[2], vd2[2];
#pragma unroll
  for (int j = 0; j < 2; j++) {
    qd2[j] = (qa1[2 * j] - qa1[2 * j + 1]) * c;
    qa2[j] = (qa1[2 * j] + qa1[2 * j + 1]) * c;
    vd2[j] = (va1[2 * j] - va1[2 * j + 1]) * c;
    va2[j] = (va1[2 * j] + va1[2 * j + 1]) * c;
  }
  const float qd3 = (qa2[0] - qa2[1]) * c, qa3 = (qa2[0] + qa2[1]) * c;
  const float vd3 = (va2[0] - va2[1]) * c, va3 = (va2[0] + va2[1]) * c;
  const float pa = (qa3 * wq0) * (va3 * wv0);
  const float pd3 = (qd3 * wq1) * (vd3 * wv1);
  float pd2[2], pd1[4];
#pragma unroll
  for (int j = 0; j < 2; j++) pd2[j] = (qd2[j] * wq2) * (vd2[j] * wv2);
#pragma unroll
  for (int i = 0; i < 4; i++) pd1[i] = qd1[i] * vd1[i];
  float s2[2], s1[4];
  s2[0] = (pa + pd3) * c;
  s2[1] = (pa - pd3) * c;
#pragma unroll
  for (int j = 0; j < 2; j++) {
    s1[2 * j] = (s2[j] + pd2[j]) * c;
    s1[2 * j + 1] = (s2[j] - pd2[j]) * c;
  }
#pragma unroll
  for (int i = 0; i < 4; i++) {
    a8[2 * i] = (s1[i] + pd1[i]) * c;
    a8[2 * i + 1] = (s1[i] - pd1[i]) * c;
  }
}

// ---- 256x256 GEMM, 8 waves (2M x 4N), R8 4-phase/K-tile schedule ----
// AF32=true: A is fp32 in global, staged via registers at R9's A-stage slots:
//   p2(t): ds_write A(t+2) from ar, then issue 8x global_load_dwordx4 A(t+3).
//   Issue->consume distance = 4 phases (one full K-tile) >> HBM latency.
// vmem ledger (B=4 gld_lds/tile @p0/p1; A=8 dwordx4/tile @p2):
//   p0(t) entry outstanding = [B(t) x4 (oldest), A(t+2) x8] -> manual vmcnt(8)
//   drains B only (t <= NT-3; later tiles: vmcnt(0)).  Compiler scoreboard
//   inserts the tight wait for ar at p2 (its own tracking is conservative
//   across opaque asm waits -> never under-waits).
// Overwrite safety: lgkm(0)+barrier at p2/p3 (R9-verified) covers the ds_writes.
// FUSED=true: B panel = W rows {d0..+127} U {1024+d0..+127}; epilogue runs the
//   Haar middle via transposed XOR-swizzled LDS c-tile, writes a[M][1024] f16.
// LDS swizzle: chunk' = chunk ^ (row&7), both-sides.  T1 XCD swizzle.  T5 setprio.

#define STAGEH(bufi, mat, half, Gbase, k0)                         \
  {                                                                \
    f16* Ld = &lds[bufi][mat][half][0];                            \
    const f16* Gp = (Gbase) + (size_t)srow * K + (k0) + sch * 8;   \
    gld_lds16(Gp, Ld + (w * 64) * 8);                              \
    gld_lds16(Gp + (size_t)64 * K, Ld + (4096 + w * 64 * 8));      \
  }

// issue 8 dwordx4 f32 loads for A tile at k0; slice sl covers rows sl*64+srow
#define A_ISSUE(k0)                                                               \
  {                                                                               \
    _Pragma("unroll") for (int sl = 0; sl < 4; sl++) {                            \
      const float* gp = A32 + (size_t)(m0 + sl * 64 + srow) * K + (k0) + sch * 8; \
      ar[sl][0] = *(const float4*)gp;                                             \
      ar[sl][1] = *(const float4*)(gp + 4);                                       \
    }                                                                             \
  }

// cvt + ds_write staged A into buf's A halves (same slot map as gld_lds path)
#define A_WRITE(bufi)                                                        \
  {                                                                          \
    _Pragma("unroll") for (int sl = 0; sl < 4; sl++) {                       \
      f16x8 y;                                                               \
      _Pragma("unroll") for (int j = 0; j < 4; j++) {                        \
        y[j] = (f16)ar[sl][0][j];                                            \
        y[j + 4] = (f16)ar[sl][1][j];                                        \
      }                                                                      \
      *(f16x8*)(&lds[bufi][0][sl >> 1][0] + ((sl & 1) * 512 + t) * 8) = y;   \
    }                                                                        \
  }

#define MFMA_PH(mi0)                                                             \
  __builtin_amdgcn_s_setprio(1);                                                 \
  _Pragma("unroll") for (int mm = (mi0); mm < (mi0) + 2; mm++)                   \
      _Pragma("unroll") for (int nj = 0; nj < 4; nj++) {                         \
    acc[mm][nj] = __builtin_amdgcn_mfma_f32_16x16x32_f16(aF[mm][0], bF[nj][0],   \
                                                         acc[mm][nj], 0, 0, 0);  \
    acc[mm][nj] = __builtin_amdgcn_mfma_f32_16x16x32_f16(aF[mm][1], bF[nj][1],   \
                                                         acc[mm][nj], 0, 0, 0);  \
  }                                                                              \
  __builtin_amdgcn_s_setprio(0);

#define BAR_SEQ()                       \
  __builtin_amdgcn_sched_barrier(0);    \
  __builtin_amdgcn_s_barrier();         \
  __builtin_amdgcn_sched_barrier(0);

template <typename CT, bool FUSED, bool AF32>
__global__ __launch_bounds__(512, 2) void gemm256_k(const f16* __restrict__ A,
                                                    const f16* __restrict__ B,
                                                    const float* __restrict__ bias,
                                                    CT* __restrict__ C,
                                                    const float* __restrict__ wq,
                                                    const float* __restrict__ wv,
                                                    const float* __restrict__ A32,
                                                    int M, int N, int K, int nbx) {
  __shared__ f16 lds[2][2][2][128 * 64];  // 128 KiB
  const int t = threadIdx.x;
  const int w = t >> 6, l = t & 63;
  const int wm = w >> 2, wn = w & 3;  // 2 x 4 wave grid
  const int hi = l >> 4, lo = l & 15;

  // T1: bijective XCD swizzle (nwg % 8 == 0)
  const int nwg = gridDim.x;
  const int cpx = nwg >> 3;
  const int bid = blockIdx.x;
  const int nid = (bid & 7) * cpx + (bid >> 3);
  const int by = nid / nbx, bx = nid - by * nbx;
  const int m0 = by * 256;
  const int n0 = bx * 256;   // non-fused col base
  const int d0 = bx * 128;   // fused dim base

  const f16* GA = A + (size_t)m0 * K;
  const f16* GBq = FUSED ? (B + (size_t)d0 * K) : (B + (size_t)n0 * K);
  const f16* GBv = FUSED ? (B + (size_t)(1024 + d0) * K) : (GBq + (size_t)128 * K);

  // staging slot map: load i covers slot u = i*512 + t per half-plane;
  // row = u>>3, chunk = (u&7) ^ (row&7)  [inverse swizzle on source]
  const int srow = t >> 3;
  const int sch = (t & 7) ^ (srow & 7);

  const int colk0 = ((hi ^ (lo & 7)) << 3);
  const int colk1 = (((4 | hi) ^ (lo & 7)) << 3);

  f32x4 acc[8][4] = {};
  f16x8 aF[8][2], bF[4][2];
  float4 ar[4][2];
  const int NT = K >> 6;  // 16

  // prologue
  if (AF32) {
    A_ISSUE(0);                           // A(0) -> ar
    STAGEH(0, 1, 0, GBq, 0);              // B(0) h0
    STAGEH(0, 1, 1, GBv, 0);              // B(0) h1
    A_WRITE(0);                           // compiler waits ar; buf0 A = tile0
    A_ISSUE(64);
    A_WRITE(1);                           // buf1 A = tile1
    A_ISSUE(128);                         // ar = tile2 (consumed at p2 of tt=0)
    asm volatile("s_waitcnt lgkmcnt(0)" ::: "memory");  // ds_writes drained
  } else {
    STAGEH(0, 1, 0, GBq, 0);
    STAGEH(0, 1, 1, GBv, 0);
    STAGEH(0, 0, 0, GA, 0); STAGEH(0, 0, 1, GA + (size_t)128 * K, 0);
    STAGEH(1, 0, 0, GA, 64); STAGEH(1, 0, 1, GA + (size_t)128 * K, 64);
  }

  for (int tt = 0; tt < NT; ++tt) {
    const int buf = tt & 1;
    const f16* pA = &lds[buf][0][wm][0] + lo * 64;
    const f16* pB = &lds[buf][1][wn >> 1][0] + (wn & 1) * 4096 + lo * 64;
    const f16* pA0 = pA + colk0;
    const f16* pA1 = pA + colk1;
    const f16* pB0 = pB + colk0;
    const f16* pB1 = pB + colk1;

    // phase 0 — drain B(t); keep A reg-loads (t<=NT-3: 8 outstanding) in flight
    if (AF32) {
      if (tt <= NT - 3) {
        asm volatile("s_waitcnt vmcnt(8)" ::: "memory");
      } else {
        asm volatile("s_waitcnt vmcnt(0)" ::: "memory");
      }
    } else {
      if (tt < NT - 1) {
        asm volatile("s_waitcnt vmcnt(4)" ::: "memory");
      } else {
        asm volatile("s_waitcnt vmcnt(0)" ::: "memory");
      }
    }
    BAR_SEQ();
    aF[0][0] = *(const f16x8*)(pA0 + 0 * 1024);
    aF[0][1] = *(const f16x8*)(pA1 + 0 * 1024);
    aF[1][0] = *(const f16x8*)(pA0 + 1 * 1024);
    aF[1][1] = *(const f16x8*)(pA1 + 1 * 1024);
#pragma unroll
    for (int nj = 0; nj < 4; nj++) {
      bF[nj][0] = *(const f16x8*)(pB0 + nj * 1024);
      bF[nj][1] = *(const f16x8*)(pB1 + nj * 1024);
    }
    aF[2][0] = *(const f16x8*)(pA0 + 2 * 1024);
    aF[2][1] = *(const f16x8*)(pA1 + 2 * 1024);
    aF[3][0] = *(const f16x8*)(pA0 + 3 * 1024);
    aF[3][1] = *(const f16x8*)(pA1 + 3 * 1024);
    if (tt + 1 < NT) STAGEH(buf ^ 1, 1, 0, GBq, (tt + 1) * 64);
    MFMA_PH(0);

    // phase 1
    BAR_SEQ();
#pragma unroll
    for (int mi = 4; mi < 8; mi++) {
      aF[mi][0] = *(const f16x8*)(pA0 + mi * 1024);
      aF[mi][1] = *(const f16x8*)(pA1 + mi * 1024);
    }
    if (tt + 1 < NT) STAGEH(buf ^ 1, 1, 1, GBv, (tt + 1) * 64);
    MFMA_PH(2);

    // phase 2: all waves' A(t) reads returned (lgkm drain + barrier) ->
    // safe to overwrite same-buf A halves with tile t+2 data
    asm volatile("s_waitcnt lgkmcnt(0)" ::: "memory");
    BAR_SEQ();
    if (AF32) {
      if (tt + 2 < NT) A_WRITE(buf);          // write A(t+2) (ar, issued @p2(t-1))
      if (tt + 3 < NT) A_ISSUE((tt + 3) * 64);  // refill ar for A(t+3)
    } else {
      if (tt + 2 < NT) STAGEH(buf, 0, 0, GA, (tt + 2) * 64);
    }
    MFMA_PH(4);

    // phase 3
    asm volatile("s_waitcnt lgkmcnt(0)" ::: "memory");
    BAR_SEQ();
    if (!AF32 && tt + 2 < NT) STAGEH(buf, 0, 1, GA + (size_t)128 * K, (tt + 2) * 64);
    MFMA_PH(6);
  }

  if (!FUSED) {
    // plain epilogue: C/D layout col = lane&15, row = (lane>>4)*4 + reg
#pragma unroll
    for (int mi = 0; mi < 8; mi++) {
#pragma unroll
      for (int nj = 0; nj < 4; nj++) {
        const int col = n0 + wn * 64 + nj * 16 + lo;
        const float bb = bias[col];
        const size_t base = (size_t)(m0 + wm * 128 + mi * 16 + hi * 4) * N + col;
#pragma unroll
        for (int r = 0; r < 4; r++) C[base + (size_t)r * N] = (CT)(acc[mi][nj][r] + bb);
      }
    }
  } else {
    // fused Haar-middle epilogue (R9-verified).
    char* ctb = (char*)&lds[0][0][0][0];  // 128 KiB c-tile, LDS dead now
#pragma unroll
    for (int mi = 0; mi < 8; mi++) {
#pragma unroll
      for (int nj = 0; nj < 4; nj++) {
        const int col = wn * 64 + nj * 16 + lo;
        const int bidx = (col < 128) ? (d0 + col) : (1024 + d0 + col - 128);
        const float bb = bias[bidx];
        f16x4 y;
#pragma unroll
        for (int r = 0; r < 4; r++) y[r] = (f16)(acc[mi][nj][r] + bb);
        const int row2 = (wm * 128 + mi * 16 + hi * 4) * 2;
        const int byte = (col * 512 + row2) ^ ((col & 7) << 4);
        *(f16x4*)(ctb + byte) = y;
      }
    }
    asm volatile("s_waitcnt lgkmcnt(0)" ::: "memory");
    __builtin_amdgcn_s_barrier();
#pragma unroll 1
    for (int p = 0; p < 8; ++p) {
      const int c = t & 127;
      const int g = p * 4 + (t >> 7);
      const int byq = (c * 512 + g * 16) ^ ((c & 7) << 4);
      const f16x8 q8 = *(const f16x8*)(ctb + byq);
      const f16x8 v8 = *(const f16x8*)(ctb + byq + 65536);
      const int d = d0 + c;
      const int wb = (d >> 6) * 192 + (d & 63);
      float a8[8];
      haar_mid(q8, v8, wq[wb], wq[wb + 64], wq[wb + 128],
               wv[wb], wv[wb + 64], wv[wb + 128], a8);
      const size_t rb = (size_t)(m0 + g * 8) * 1024 + d;
#pragma unroll
      for (int i = 0; i < 8; i++) C[rb + (size_t)i * 1024] = (CT)a8[i];
    }
  }
}

// ---------------- standalone wavelet middle (ws-fallback path) ----------------
__global__ __launch_bounds__(256) void dwt_middle_k(const f16* __restrict__ qv,
                                                    const float* __restrict__ wq,
                                                    const float* __restrict__ wv,
                                                    f16* __restrict__ out) {
  const int g = blockIdx.x;
  const int d0 = threadIdx.x * 4;
  const size_t m0 = (size_t)g * 8;
  f16x4 qr[8], vr[8], o[8];
#pragma unroll
  for (int i = 0; i < 8; i++) {
    qr[i] = *(const f16x4*)(qv + (m0 + i) * 2048 + d0);
    vr[i] = *(const f16x4*)(qv + (m0 + i) * 2048 + 1024 + d0);
  }
#pragma unroll
  for (int dd = 0; dd < 4; dd++) {
    const int d = d0 + dd;
    const int wb = (d >> 6) * 192 + (d & 63);
    f16x8 q8, v8;
#pragma unroll
    for (int i = 0; i < 8; i++) { q8[i] = qr[i][dd]; v8[i] = vr[i][dd]; }
    float a8[8];
    haar_mid(q8, v8, wq[wb], wq[wb + 64], wq[wb + 128],
             wv[wb], wv[wb + 64], wv[wb + 128], a8);
#pragma unroll
    for (int i = 0; i < 8; i++) o[i][dd] = (f16)a8[i];
  }
#pragma unroll
  for (int i = 0; i < 8; i++) *(f16x4*)(out + (m0 + i) * 1024 + d0) = o[i];
}

// ---------------- launch ----------------
extern "C" void kernel_launch(void* const* d_in, const int* in_sizes, int n_in,
                              void* d_out, int out_size, void* d_ws, size_t ws_size,
                              hipStream_t stream) {
  (void)in_sizes; (void)n_in; (void)out_size;
  const float* query = (const float*)d_in[0];
  const float* W_qkv = (const float*)d_in[1];
  const float* b_qkv = (const float*)d_in[2];
  const float* W_out = (const float*)d_in[3];
  const float* b_out = (const float*)d_in[4];
  const float* wq = (const float*)d_in[5];
  const float* wv = (const float*)d_in[6];
  float* out = (float*)d_out;

  // workspace layout: [0,64MB) = a (fused) or qf16 (fallback); then weights
  char* ws = (char*)d_ws;
  f16* reg0 = (f16*)ws;                                // 67,108,864 B
  f16* Wqv = (f16*)(ws + 67108864);                    //  4,194,304 B
  float* bqv = (float*)(ws + 67108864 + 4194304);      //      8,192 B
  f16* Wout = (f16*)(ws + 67108864 + 4194304 + 8192);  //  2,097,152 B
  const size_t NEED = 67108864UL + 4194304 + 8192 + 2097152;  // 73,408,512

  pack_wqv_k<<<dim3(2048), dim3(256), 0, stream>>>(W_qkv, b_qkv, Wqv, bqv);
  cvt_f32_f16_k<<<dim3(262144 / 256), dim3(256), 0, stream>>>(W_out, Wout, 262144);

  if (ws_size >= NEED) {
    // fused path: GEMM1 stages A from f32 query in-kernel (no cvt_query),
    // Haar middle in epilogue -> a at ws+0; no qv, no middle kernel
    f16* a_f16 = reg0;
    gemm256_k<f16, true, true><<<dim3(8 * 128), dim3(512), 0, stream>>>(
        nullptr, Wqv, bqv, a_f16, wq, wv, query, 32768, 1024, 1024, 8);
    gemm256_k<float, false, false><<<dim3(4 * 128), dim3(512), 0, stream>>>(
        a_f16, Wout, b_out, out, nullptr, nullptr, nullptr, 32768, 1024, 1024, 4);
  } else {
    // fallback (R8-verified 3-kernel path): qv in d_out, a aliases qf16
    f16* qf16 = reg0;
    cvt_f32_f16_k<<<dim3(8388608 / 256), dim3(256), 0, stream>>>(query, qf16, 8388608);
    f16* qv = (f16*)d_out;
    gemm256_k<f16, false, false><<<dim3(8 * 128), dim3(512), 0, stream>>>(
        qf16, Wqv, bqv, qv, nullptr, nullptr, nullptr, 32768, 2048, 1024, 8);
    dwt_middle_k<<<dim3(4096), dim3(256), 0, stream>>>(qv, wq, wv, qf16);
    gemm256_k<float, false, false><<<dim3(4 * 128), dim3(512), 0, stream>>>(
        qf16, Wout, b_out, out, nullptr, nullptr, nullptr, 32768, 1024, 1024, 4);
  }
}

// Round 13
// 268.567 us; speedup vs baseline: 1.6070x; 1.3680x over previous
//
#include <hip/hip_runtime.h>
#include <hip/hip_fp16.h>
#include <cstdint>
#include <cstddef>

typedef _Float16 f16;
typedef __attribute__((ext_vector_type(4))) _Float16 f16x4;
typedef __attribute__((ext_vector_type(8))) _Float16 f16x8;
typedef __attribute__((ext_vector_type(4))) float f32x4;

#define C_INV_SQRT2 0.70710678118654752440f

__device__ __forceinline__ void gld_lds16(const void* g, void* l) {
  __builtin_amdgcn_global_load_lds((const __attribute__((address_space(1))) void*)g,
                                   (__attribute__((address_space(3))) void*)l, 16, 0, 0);
}

// ---------------- conversion kernels ----------------
__global__ __launch_bounds__(256) void cvt_f32_f16_k(const float* __restrict__ in,
                                                     f16* __restrict__ out, int n4) {
  int i = blockIdx.x * 256 + threadIdx.x;
  if (i >= n4) return;
  const float4 x = ((const float4*)in)[i];
  f16x4 y;
  y.x = (f16)x.x; y.y = (f16)x.y; y.z = (f16)x.z; y.w = (f16)x.w;
  ((f16x4*)out)[i] = y;
}

// pack W_qkv rows {0..1023} and {2048..3071} into Wo[2048][1024] f16; same for bias
__global__ __launch_bounds__(256) void pack_wqv_k(const float* __restrict__ W,
                                                  const float* __restrict__ b,
                                                  f16* __restrict__ Wo,
                                                  float* __restrict__ bo) {
  int i = blockIdx.x * 256 + threadIdx.x;
  int n = i >> 8;
  int c = (i & 255) * 4;
  int sn = (n < 1024) ? n : (n + 1024);
  const float4 x = *(const float4*)(W + (size_t)sn * 1024 + c);
  f16x4 y; y.x = (f16)x.x; y.y = (f16)x.y; y.z = (f16)x.z; y.w = (f16)x.w;
  *(f16x4*)(Wo + (size_t)n * 1024 + c) = y;
  if (i < 2048) bo[i] = b[(i < 1024) ? i : (i + 1024)];
}

// -------- 3-level Haar forward + weighted product + inverse, 8 samples --------
__device__ __forceinline__ void haar_mid(const f16x8 q8, const f16x8 v8,
                                         float wq0, float wq1, float wq2,
                                         float wv0, float wv1, float wv2,
                                         float* a8) {
  const float c = C_INV_SQRT2;
  float q[8], v[8];
#pragma unroll
  for (int i = 0; i < 8; i++) { q[i] = (float)q8[i]; v[i] = (float)v8[i]; }
  float qa1[4], qd1[4], va1[4], vd1[4];
#pragma unroll
  for (int i = 0; i < 4; i++) {
    qd1[i] = (q[2 * i] - q[2 * i + 1]) * c;
    qa1[i] = (q[2 * i] + q[2 * i + 1]) * c;
    vd1[i] = (v[2 * i] - v[2 * i + 1]) * c;
    va1[i] = (v[2 * i] + v[2 * i + 1]) * c;
  }
  float qa2[2], qd2[2], va2[2], vd2[2];
#pragma unroll
  for (int j = 0; j < 2; j++) {
    qd2[j] = (qa1[2 * j] - qa1[2 * j + 1]) * c;
    qa2[j] = (qa1[2 * j] + qa1[2 * j + 1]) * c;
    vd2[j] = (va1[2 * j] - va1[2 * j + 1]) * c;
    va2[j] = (va1[2 * j] + va1[2 * j + 1]) * c;
  }
  const float qd3 = (qa2[0] - qa2[1]) * c, qa3 = (qa2[0] + qa2[1]) * c;
  const float vd3 = (va2[0] - va2[1]) * c, va3 = (va2[0] + va2[1]) * c;
  const float pa = (qa3 * wq0) * (va3 * wv0);
  const float pd3 = (qd3 * wq1) * (vd3 * wv1);
  float pd2[2], pd1[4];
#pragma unroll
  for (int j = 0; j < 2; j++) pd2[j] = (qd2[j] * wq2) * (vd2[j] * wv2);
#pragma unroll
  for (int i = 0; i < 4; i++) pd1[i] = qd1[i] * vd1[i];
  float s2[2], s1[4];
  s2[0] = (pa + pd3) * c;
  s2[1] = (pa - pd3) * c;
#pragma unroll
  for (int j = 0; j < 2; j++) {
    s1[2 * j] = (s2[j] + pd2[j]) * c;
    s1[2 * j + 1] = (s2[j] - pd2[j]) * c;
  }
#pragma unroll
  for (int i = 0; i < 4; i++) {
    a8[2 * i] = (s1[i] + pd1[i]) * c;
    a8[2 * i + 1] = (s1[i] - pd1[i]) * c;
  }
}

// ---- 256x256 GEMM, 8 waves (2M x 4N), 4-phase/K-tile + phase-level read-ahead ----
// C[M,N] = A[M,K]*B[N,K]^T + bias.  512 threads; per-wave output 128(M) x 64(N).
// K-tile BK=64; LDS = 2 buf x {A,B} x 2 halves x [128 rows x 64 f16] = 128 KiB.
// Stages (R9-verified slots): p0(t): Bh0(t+1); p1(t): Bh1(t+1);
//                             p2(t): Ah0(t+2); p3(t): Ah1(t+2).
// READ SCHEDULE (new vs R9): frags read ONE PHASE EARLY so each MFMA cluster
// starts with no lgkm head-wait and reads overlap MFMA:
//   p0: vmcnt(4) [B(t) landed; A(t+1) 4 in flight] -> bar -> read B all (8) +
//       A mi2,3 (4) -> stage Bh0(t+1) -> MFMA mi0,1 (frags pre-read @p3(t-1))
//   p1: bar -> read A mi4..7 (8) -> stage Bh1(t+1) -> MFMA mi2,3
//   p2: lgkm(0) -> bar -> stage Ah0(t+2) -> MFMA mi4,5      (no reads)
//   p3: lgkm(0) -> vmcnt(6|4) [certify A(t+1) landed, pre-barrier] -> bar ->
//       read A(t+1) mi0,1 from buf^1 (4) -> stage Ah1(t+2) -> MFMA mi6,7
// vmem ledger pre-barrier @p3(t): [Ah1(t+1)2 oldest, B(t+1)4, Ah0(t+2)2] ->
//   keep 4+(tt+2<NT?2:0).  @p0(t): [B(t)4 oldest, A(t+1)4] -> keep 4 (last: 0).
// Overwrite safety: all tile-t frag reads issued by p1(t); lgkm(0)+barrier at
// p2/p3 certify before the A-half overwrites (R9-verified invariant).
// LDS swizzle chunk^=(row&7) both-sides.  T1 XCD swizzle.  T5 setprio.

#define STAGEH(bufi, mat, half, Gbase, k0)                         \
  {                                                                \
    f16* Ld = &lds[bufi][mat][half][0];                            \
    const f16* Gp = (Gbase) + (size_t)srow * K + (k0) + sch * 8;   \
    gld_lds16(Gp, Ld + (w * 64) * 8);                              \
    gld_lds16(Gp + (size_t)64 * K, Ld + (4096 + w * 64 * 8));      \
  }

#define MFMA_PH(mi0)                                                             \
  __builtin_amdgcn_s_setprio(1);                                                 \
  _Pragma("unroll") for (int mm = (mi0); mm < (mi0) + 2; mm++)                   \
      _Pragma("unroll") for (int nj = 0; nj < 4; nj++) {                         \
    acc[mm][nj] = __builtin_amdgcn_mfma_f32_16x16x32_f16(aF[mm][0], bF[nj][0],   \
                                                         acc[mm][nj], 0, 0, 0);  \
    acc[mm][nj] = __builtin_amdgcn_mfma_f32_16x16x32_f16(aF[mm][1], bF[nj][1],   \
                                                         acc[mm][nj], 0, 0, 0);  \
  }                                                                              \
  __builtin_amdgcn_s_setprio(0);

#define BAR_SEQ()                       \
  __builtin_amdgcn_sched_barrier(0);    \
  __builtin_amdgcn_s_barrier();         \
  __builtin_amdgcn_sched_barrier(0);

template <typename CT, bool FUSED>
__global__ __launch_bounds__(512, 2) void gemm256_k(const f16* __restrict__ A,
                                                    const f16* __restrict__ B,
                                                    const float* __restrict__ bias,
                                                    CT* __restrict__ C,
                                                    const float* __restrict__ wq,
                                                    const float* __restrict__ wv,
                                                    int M, int N, int K, int nbx) {
  __shared__ f16 lds[2][2][2][128 * 64];  // 128 KiB
  const int t = threadIdx.x;
  const int w = t >> 6, l = t & 63;
  const int wm = w >> 2, wn = w & 3;  // 2 x 4 wave grid
  const int hi = l >> 4, lo = l & 15;

  // T1: bijective XCD swizzle (nwg % 8 == 0)
  const int nwg = gridDim.x;
  const int cpx = nwg >> 3;
  const int bid = blockIdx.x;
  const int nid = (bid & 7) * cpx + (bid >> 3);
  const int by = nid / nbx, bx = nid - by * nbx;
  const int m0 = by * 256;
  const int n0 = bx * 256;   // non-fused col base
  const int d0 = bx * 128;   // fused dim base

  const f16* GA = A + (size_t)m0 * K;
  const f16* GBq = FUSED ? (B + (size_t)d0 * K) : (B + (size_t)n0 * K);
  const f16* GBv = FUSED ? (B + (size_t)(1024 + d0) * K) : (GBq + (size_t)128 * K);

  // staging slot map: load i covers slot u = i*512 + t per half-plane;
  // row = u>>3, chunk = (u&7) ^ (row&7)  [inverse swizzle on source]
  const int srow = t >> 3;
  const int sch = (t & 7) ^ (srow & 7);

  const int colk0 = ((hi ^ (lo & 7)) << 3);
  const int colk1 = (((4 | hi) ^ (lo & 7)) << 3);

  f32x4 acc[8][4] = {};
  f16x8 aF[8][2], bF[4][2];
  const int NT = K >> 6;  // K=1024 -> 16

  // prologue: A(0), B(0) into buf0; A(1) into buf1  (12 loads)
  STAGEH(0, 0, 0, GA, 0); STAGEH(0, 0, 1, GA + (size_t)128 * K, 0);
  STAGEH(0, 1, 0, GBq, 0); STAGEH(0, 1, 1, GBv, 0);
  STAGEH(1, 0, 0, GA, 64); STAGEH(1, 0, 1, GA + (size_t)128 * K, 64);
  // certify A(0) landed (drain 4 oldest of 12), then pre-read tile0 mi0,1
  asm volatile("s_waitcnt vmcnt(8)" ::: "memory");
  __builtin_amdgcn_s_barrier();
  __builtin_amdgcn_sched_barrier(0);
  {
    const f16* qA = &lds[0][0][wm][0] + lo * 64;
    aF[0][0] = *(const f16x8*)(qA + colk0 + 0 * 1024);
    aF[0][1] = *(const f16x8*)(qA + colk1 + 0 * 1024);
    aF[1][0] = *(const f16x8*)(qA + colk0 + 1 * 1024);
    aF[1][1] = *(const f16x8*)(qA + colk1 + 1 * 1024);
  }

  for (int tt = 0; tt < NT; ++tt) {
    const int buf = tt & 1;
    const f16* pA = &lds[buf][0][wm][0] + lo * 64;
    const f16* pB = &lds[buf][1][wn >> 1][0] + (wn & 1) * 4096 + lo * 64;
    const f16* pA0 = pA + colk0;
    const f16* pA1 = pA + colk1;
    const f16* pB0 = pB + colk0;
    const f16* pB1 = pB + colk1;

    // ---------------- phase 0: B(t) must be landed chip-wide
    if (tt < NT - 1) {
      asm volatile("s_waitcnt vmcnt(4)" ::: "memory");
    } else {
      asm volatile("s_waitcnt vmcnt(0)" ::: "memory");
    }
    BAR_SEQ();
#pragma unroll
    for (int nj = 0; nj < 4; nj++) {
      bF[nj][0] = *(const f16x8*)(pB0 + nj * 1024);
      bF[nj][1] = *(const f16x8*)(pB1 + nj * 1024);
    }
    aF[2][0] = *(const f16x8*)(pA0 + 2 * 1024);
    aF[2][1] = *(const f16x8*)(pA1 + 2 * 1024);
    aF[3][0] = *(const f16x8*)(pA0 + 3 * 1024);
    aF[3][1] = *(const f16x8*)(pA1 + 3 * 1024);
    if (tt + 1 < NT) STAGEH(buf ^ 1, 1, 0, GBq, (tt + 1) * 64);
    MFMA_PH(0);  // aF[0,1] pre-read at p3(t-1) / prologue

    // ---------------- phase 1: read mi4..7 (for p2,p3), MFMA mi2,3
    BAR_SEQ();
#pragma unroll
    for (int mi = 4; mi < 8; mi++) {
      aF[mi][0] = *(const f16x8*)(pA0 + mi * 1024);
      aF[mi][1] = *(const f16x8*)(pA1 + mi * 1024);
    }
    if (tt + 1 < NT) STAGEH(buf ^ 1, 1, 1, GBv, (tt + 1) * 64);
    MFMA_PH(2);

    // ---------------- phase 2: no reads; stage Ah0(t+2); MFMA mi4,5
    asm volatile("s_waitcnt lgkmcnt(0)" ::: "memory");
    BAR_SEQ();
    if (tt + 2 < NT) STAGEH(buf, 0, 0, GA, (tt + 2) * 64);
    MFMA_PH(4);

    // ---------------- phase 3: certify A(t+1), read-ahead its mi0,1; MFMA mi6,7
    asm volatile("s_waitcnt lgkmcnt(0)" ::: "memory");
    if (tt + 1 < NT) {
      if (tt + 2 < NT) {
        asm volatile("s_waitcnt vmcnt(6)" ::: "memory");
      } else {
        asm volatile("s_waitcnt vmcnt(4)" ::: "memory");
      }
    }
    BAR_SEQ();
    if (tt + 1 < NT) {
      const f16* qA = &lds[buf ^ 1][0][wm][0] + lo * 64;
      aF[0][0] = *(const f16x8*)(qA + colk0 + 0 * 1024);
      aF[0][1] = *(const f16x8*)(qA + colk1 + 0 * 1024);
      aF[1][0] = *(const f16x8*)(qA + colk0 + 1 * 1024);
      aF[1][1] = *(const f16x8*)(qA + colk1 + 1 * 1024);
    }
    if (tt + 2 < NT) STAGEH(buf, 0, 1, GA + (size_t)128 * K, (tt + 2) * 64);
    MFMA_PH(6);
  }

  if (!FUSED) {
    // plain epilogue: C/D layout col = lane&15, row = (lane>>4)*4 + reg
#pragma unroll
    for (int mi = 0; mi < 8; mi++) {
#pragma unroll
      for (int nj = 0; nj < 4; nj++) {
        const int col = n0 + wn * 64 + nj * 16 + lo;
        const float bb = bias[col];
        const size_t base = (size_t)(m0 + wm * 128 + mi * 16 + hi * 4) * N + col;
#pragma unroll
        for (int r = 0; r < 4; r++) C[base + (size_t)r * N] = (CT)(acc[mi][nj][r] + bb);
      }
    }
  } else {
    // fused Haar-middle epilogue (R9-verified).
    char* ctb = (char*)&lds[0][0][0][0];  // 128 KiB c-tile, LDS dead now
#pragma unroll
    for (int mi = 0; mi < 8; mi++) {
#pragma unroll
      for (int nj = 0; nj < 4; nj++) {
        const int col = wn * 64 + nj * 16 + lo;
        const int bidx = (col < 128) ? (d0 + col) : (1024 + d0 + col - 128);
        const float bb = bias[bidx];
        f16x4 y;
#pragma unroll
        for (int r = 0; r < 4; r++) y[r] = (f16)(acc[mi][nj][r] + bb);
        const int row2 = (wm * 128 + mi * 16 + hi * 4) * 2;
        const int byte = (col * 512 + row2) ^ ((col & 7) << 4);
        *(f16x4*)(ctb + byte) = y;
      }
    }
    asm volatile("s_waitcnt lgkmcnt(0)" ::: "memory");
    __builtin_amdgcn_s_barrier();
#pragma unroll 1
    for (int p = 0; p < 8; ++p) {
      const int c = t & 127;
      const int g = p * 4 + (t >> 7);
      const int byq = (c * 512 + g * 16) ^ ((c & 7) << 4);
      const f16x8 q8 = *(const f16x8*)(ctb + byq);
      const f16x8 v8 = *(const f16x8*)(ctb + byq + 65536);
      const int d = d0 + c;
      const int wb = (d >> 6) * 192 + (d & 63);
      float a8[8];
      haar_mid(q8, v8, wq[wb], wq[wb + 64], wq[wb + 128],
               wv[wb], wv[wb + 64], wv[wb + 128], a8);
      const size_t rb = (size_t)(m0 + g * 8) * 1024 + d;
#pragma unroll
      for (int i = 0; i < 8; i++) C[rb + (size_t)i * 1024] = (CT)a8[i];
    }
  }
}

// ---------------- standalone wavelet middle (ws-fallback path) ----------------
__global__ __launch_bounds__(256) void dwt_middle_k(const f16* __restrict__ qv,
                                                    const float* __restrict__ wq,
                                                    const float* __restrict__ wv,
                                                    f16* __restrict__ out) {
  const int g = blockIdx.x;
  const int d0 = threadIdx.x * 4;
  const size_t m0 = (size_t)g * 8;
  f16x4 qr[8], vr[8], o[8];
#pragma unroll
  for (int i = 0; i < 8; i++) {
    qr[i] = *(const f16x4*)(qv + (m0 + i) * 2048 + d0);
    vr[i] = *(const f16x4*)(qv + (m0 + i) * 2048 + 1024 + d0);
  }
#pragma unroll
  for (int dd = 0; dd < 4; dd++) {
    const int d = d0 + dd;
    const int wb = (d >> 6) * 192 + (d & 63);
    f16x8 q8, v8;
#pragma unroll
    for (int i = 0; i < 8; i++) { q8[i] = qr[i][dd]; v8[i] = vr[i][dd]; }
    float a8[8];
    haar_mid(q8, v8, wq[wb], wq[wb + 64], wq[wb + 128],
             wv[wb], wv[wb + 64], wv[wb + 128], a8);
#pragma unroll
    for (int i = 0; i < 8; i++) o[i][dd] = (f16)a8[i];
  }
#pragma unroll
  for (int i = 0; i < 8; i++) *(f16x4*)(out + (m0 + i) * 1024 + d0) = o[i];
}

// ---------------- launch ----------------
extern "C" void kernel_launch(void* const* d_in, const int* in_sizes, int n_in,
                              void* d_out, int out_size, void* d_ws, size_t ws_size,
                              hipStream_t stream) {
  (void)in_sizes; (void)n_in; (void)out_size;
  const float* query = (const float*)d_in[0];
  const float* W_qkv = (const float*)d_in[1];
  const float* b_qkv = (const float*)d_in[2];
  const float* W_out = (const float*)d_in[3];
  const float* b_out = (const float*)d_in[4];
  const float* wq = (const float*)d_in[5];
  const float* wv = (const float*)d_in[6];
  float* out = (float*)d_out;

  // workspace layout (R9-verified)
  char* ws = (char*)d_ws;
  f16* qf16 = (f16*)ws;                                // 67,108,864 B
  f16* Wqv = (f16*)(ws + 67108864);                    //  4,194,304 B
  float* bqv = (float*)(ws + 67108864 + 4194304);      //      8,192 B
  f16* Wout = (f16*)(ws + 67108864 + 4194304 + 8192);  //  2,097,152 B
  const size_t OFS_A = 67108864UL + 4194304 + 8192 + 2097152;  // 73,408,512
  const size_t NEED = OFS_A + 67108864UL;                      // 140,517,376

  cvt_f32_f16_k<<<dim3(8388608 / 256), dim3(256), 0, stream>>>(query, qf16, 8388608);
  pack_wqv_k<<<dim3(2048), dim3(256), 0, stream>>>(W_qkv, b_qkv, Wqv, bqv);
  cvt_f32_f16_k<<<dim3(262144 / 256), dim3(256), 0, stream>>>(W_out, Wout, 262144);

  if (ws_size >= NEED) {
    // fused path: GEMM1 + Haar middle in epilogue -> a in ws; no qv, no middle kernel
    f16* a_f16 = (f16*)(ws + OFS_A);
    gemm256_k<f16, true><<<dim3(8 * 128), dim3(512), 0, stream>>>(
        qf16, Wqv, bqv, a_f16, wq, wv, 32768, 1024, 1024, 8);
    gemm256_k<float, false><<<dim3(4 * 128), dim3(512), 0, stream>>>(
        a_f16, Wout, b_out, out, nullptr, nullptr, 32768, 1024, 1024, 4);
  } else {
    // fallback: qv in d_out, a aliases qf16
    f16* qv = (f16*)d_out;
    f16* a_f16 = qf16;
    gemm256_k<f16, false><<<dim3(8 * 128), dim3(512), 0, stream>>>(
        qf16, Wqv, bqv, qv, nullptr, nullptr, 32768, 2048, 1024, 8);
    dwt_middle_k<<<dim3(4096), dim3(256), 0, stream>>>(qv, wq, wv, a_f16);
    gemm256_k<float, false><<<dim3(4 * 128), dim3(512), 0, stream>>>(
        a_f16, Wout, b_out, out, nullptr, nullptr, 32768, 1024, 1024, 4);
  }
}